// Round 12
// baseline (209.942 us; speedup 1.0000x reference)
//
#include <hip/hip_runtime.h>
#include <hip/hip_bf16.h>

// ModulatedConv2d: out = oscale[b,co] * conv2d(s[b,ci]*x, w_bf16)
// B=8, C=512, K=3, H=W=64.
// Round 12: additive-law attack. 4 fat waves/CU (1/SIMD), wave = 128co x
// 128px (2 rows), 32x32x16 MFMA (same operand bytes, 9.3k vs 11.2k cyc MFMA
// floor). Delivery: A from LDS 288 KB/CU/chunk, B from L2 288 KB. acc[4][4]
// f32x16 = 256 regs (1 wave/SIMD, spill-free < 512). W dbuf LDS, r9 schedule.

#define CDIM 512
#define HW 64
#define NCHUNK 16   // 512/32
#define XROW 2112   // shorts per xs row: 66 px-cols * 32 ci

typedef __attribute__((ext_vector_type(8))) short short8;
typedef __attribute__((ext_vector_type(4))) float float4v;
typedef __attribute__((ext_vector_type(16))) float float16v;

__device__ __forceinline__ short f2bf(float f) {
    unsigned u = __float_as_uint(f);
    unsigned r = (u + 0x7FFFu + ((u >> 16) & 1u)) >> 16;
    return (short)r;
}

__device__ __forceinline__ void async_ld16(const short* g, short* l) {
    __builtin_amdgcn_global_load_lds(
        (const __attribute__((address_space(1))) void*)g,
        (__attribute__((address_space(3))) void*)l, 16, 0, 0);
}

__device__ __forceinline__ void hard_sync() {
    asm volatile("s_waitcnt vmcnt(0) lgkmcnt(0)" ::: "memory");
    __builtin_amdgcn_sched_barrier(0);
    __builtin_amdgcn_s_barrier();
    __builtin_amdgcn_sched_barrier(0);
}

// ---------------- prep kernels ----------------

__global__ void k_affine(const float* __restrict__ style, const float* __restrict__ aw,
                         const float* __restrict__ ab, float* __restrict__ s) {
    int gid = blockIdx.x * 4 + (threadIdx.x >> 6);   // 0..4095
    int lane = threadIdx.x & 63;
    int b = gid >> 9, ci = gid & 511;
    const float4v* st = (const float4v*)(style + b * CDIM);
    const float4v* wp = (const float4v*)(aw + ci * CDIM);
    float acc = 0.f;
#pragma unroll
    for (int k = 0; k < 2; ++k) {
        float4v a = st[lane * 2 + k], w = wp[lane * 2 + k];
        acc += a[0] * w[0] + a[1] * w[1] + a[2] * w[2] + a[3] * w[3];
    }
#pragma unroll
    for (int off = 32; off; off >>= 1) acc += __shfl_down(acc, off);
    if (lane == 0) s[gid] = acc * 0.04419417382415922f + ab[ci];
}

__global__ void k_ws2(const float* __restrict__ w, float* __restrict__ ws2) {
    int i = blockIdx.x * 256 + threadIdx.x;  // 262144
    const float* p = w + i * 9;
    float a = 0.f;
#pragma unroll
    for (int t = 0; t < 9; ++t) a += p[t] * p[t];
    ws2[i] = a;
}

__global__ void k_oscale(const float* __restrict__ s, const float* __restrict__ ws2,
                         float* __restrict__ osc) {
    int gid = blockIdx.x * 4 + (threadIdx.x >> 6);   // 0..4095
    int lane = threadIdx.x & 63;
    int b = gid >> 9, co = gid & 511;
    const float4v* sp = (const float4v*)(s + b * CDIM);
    const float4v* rp = (const float4v*)(ws2 + co * CDIM);
    float acc = 0.f;
#pragma unroll
    for (int k = 0; k < 2; ++k) {
        float4v a = sp[lane * 2 + k], r = rp[lane * 2 + k];
        acc += a[0] * a[0] * r[0] + a[1] * a[1] * r[1]
             + a[2] * a[2] * r[2] + a[3] * a[3] * r[3];
    }
#pragma unroll
    for (int off = 32; off; off >>= 1) acc += __shfl_down(acc, off);
    const float wg = 0.014731391274719739f;          // 1/sqrt(4608)
    const float wg2 = 2.170138888888889e-4f;         // 1/4608
    if (lane == 0) osc[gid] = wg * rsqrtf(wg2 * acc + 1e-8f);
}

// wgt32 layout: [chunk16][ct4] regions of 36864 shorts.
// Within region: [t9][ks2][mf4][lane64][j8],
// value = w[co = ct*128 + mf*32 + (lane&31)]
//          [ci = chunk*32 + ks*16 + (lane>>5)*8 + j][t]
// (A-operand of 32x32x16: row = lane&31, k = (lane>>5)*8 + j.)
__global__ void k_wconv32(const float* __restrict__ w, short* __restrict__ wgt) {
    int idx = blockIdx.x * 256 + threadIdx.x;  // 2359296
    int j = idx & 7;
    int slotg = idx >> 3;
    int region = slotg / 4608;         // chunk*4 + ct
    int a16 = slotg - region * 4608;   // 0..4607 = ((t*2+ks)*4+mf)*64 + sl
    int sl = a16 & 63;
    int g = a16 >> 6;                  // (t*2+ks)*4 + mf
    int mf = g & 3;
    int ks = (g >> 2) & 1;
    int t = g >> 3;
    int ct = region & 3;
    int c = region >> 2;
    int co = ct * 128 + mf * 32 + (sl & 31);
    int ci = c * 32 + ks * 16 + (sl >> 5) * 8 + j;
    wgt[idx] = f2bf(w[(co * CDIM + ci) * 9 + t]);
}

// OLD wgt layout (fallback path): [chunk16][ct4] regions of 36864 shorts,
// [t9][mf8][slot64][j8], co = ct*128 + mf*16 + l15, ci = c*32 + l4*8 + j.
__global__ void k_wconv4(const float* __restrict__ w, short* __restrict__ wgt) {
    int idx = blockIdx.x * 256 + threadIdx.x;  // 2359296
    int j = idx & 7;
    int slotg = idx >> 3;
    int region = slotg / 4608;
    int a16 = slotg - region * 4608;
    int tm = a16 >> 6;
    int t = tm >> 3;
    int mf = tm & 7;
    int sl = a16 & 63;
    int l4 = sl >> 4;
    int l15 = sl & 15;
    int ct = region & 3;
    int c = region >> 2;
    int co = ct * 128 + mf * 16 + l15;
    int ci = c * 32 + l4 * 8 + j;
    wgt[idx] = f2bf(w[(co * CDIM + ci) * 9 + t]);
}

// xs layout: [b8][c16][grow64] rows of XROW=2112 shorts (66 px-cols x 32 ci):
// shorts at (px+1)*32 + sl*8 + j = bf16( x[b][ci=c*32+sl*8+j][grow][px] * s ),
// px-cols 0 and 65 are zero halos.
__global__ void k_xs(const float* __restrict__ x, const float* __restrict__ s,
                     short* __restrict__ xs) {
    const int bx = blockIdx.x;         // (b*16 + c)*64 + grow
    const int grow = bx & 63;
    const int t = bx >> 6;
    const int c = t & 15;
    const int b = t >> 4;
    const int px = threadIdx.x >> 2;   // 0..63
    const int sl = threadIdx.x & 3;    // ci 8-group
    const int ci0 = c * 32 + sl * 8;
    const float* xb = x + ((b * CDIM + ci0) * HW + grow) * HW + px;
    const float* sb = s + b * CDIM + ci0;
    short8 pk;
#pragma unroll
    for (int j = 0; j < 8; ++j)
        pk[j] = f2bf(xb[j * (HW * HW)] * sb[j]);
    short* rowp = xs + (size_t)bx * XROW;
    *(short8*)&rowp[(px + 1) * 32 + sl * 8] = pk;
    if (threadIdx.x < 8) {             // zero halo cols 0 and 65
        int col = (threadIdx.x >> 2) ? 65 : 0;
        int s2 = threadIdx.x & 3;
        short8 z = {};
        *(short8*)&rowp[col * 32 + s2 * 8] = z;
    }
}

// ---------------- main conv (v5: 32x32x16, 4 fat waves/CU) ----------------
// grid 256 blocks x 256 threads (4 waves = 1/SIMD).
// Block: (ct co-tile of 128, b, row-tile of 8). Wave: 128co x 2rows x 64px.
__global__ __launch_bounds__(256, 1) void conv_main5(
    const short* __restrict__ xs, const short* __restrict__ zrow,
    const short* __restrict__ wgt, const float* __restrict__ osc,
    float* __restrict__ out) {

    __shared__ __align__(16) short w_lds[2][36864];   // 2 x 73728 B

    const int tid = threadIdx.x;
    const int lane = tid & 63;
    const int wid = tid >> 6;          // 0..3
    const int l31 = lane & 31;
    const int lh = lane >> 5;          // 0/1

    // b == xcd; the 4 ct-blocks of one (b,rt) group share the xs slice in L2.
    const int bx = blockIdx.x;
    const int xcd = bx & 7;
    const int t7 = bx >> 3;
    const int ct = t7 & 3;
    const int rt = t7 >> 2;            // 0..7
    const int b = xcd;
    const int wave_r = rt * 8 + wid * 2;   // first of this wave's 2 output rows

    auto stage_w = [&](int c, int bufn) {   // 4608 units / 256 thr = 18 glls/thr
        const short* src = wgt + (c * 4 + ct) * 36864;
        short* dstb = &w_lds[bufn][0];
#pragma unroll
        for (int k = 0; k < 18; ++k) {
            int u = tid + 256 * k;         // 0..4607, exact
            async_ld16(src + u * 8, dstb + u * 8);
        }
    };

    float16v acc[4][4] = {};   // [mf co-32][nf: (row waveR+(nf>>1), px (nf&1)*32)]

    // one (tap, kstep) group: 4 B loads (L2) + 4 A reads (LDS) + 16 MFMA
#define GRP(T, KS)                                                               \
    { const int dh = (T) / 3 - 1;                                               \
      const int dw = (T) % 3 - 1;                                               \
      short8 bfr[4];                                                            \
      _Pragma("unroll")                                                         \
      for (int nf = 0; nf < 4; ++nf) {                                          \
          const short* pd = p[1 + (nf >> 1) + dh];                              \
          bfr[nf] = *(const short8*)(pd + ((nf & 1) * 32 + l31 + dw + 1) * 32   \
                                        + (KS) * 16 + lh * 8);                  \
      }                                                                         \
      _Pragma("unroll")                                                         \
      for (int mf = 0; mf < 4; ++mf) {                                          \
          short8 af = *(const short8*)&wb[((((T) * 2 + (KS)) * 4 + mf) * 64     \
                                           + lane) * 8];                        \
          _Pragma("unroll")                                                     \
          for (int nf = 0; nf < 4; ++nf)                                        \
              acc[mf][nf] = __builtin_amdgcn_mfma_f32_32x32x16_bf16(            \
                  af, bfr[nf], acc[mf][nf], 0, 0, 0);                           \
      } }

    // prologue: W(0) -> buf0, drain, publish
    stage_w(0, 0);
    hard_sync();

    const int gb = wave_r - 1;         // lowest input row this wave touches
#pragma unroll 1
    for (int c = 0; c < NCHUNK; ++c) {
        const int buf = c & 1;
        const short* wb = &w_lds[buf][0];
        const short* xcb = xs + ((size_t)(b * 16 + c) * 64) * XROW;
        const short* p[4];
#pragma unroll
        for (int i = 0; i < 4; ++i)
            p[i] = ((unsigned)(gb + i) < 64u) ? xcb + (size_t)(gb + i) * XROW : zrow;

        GRP(0, 0)
        // next-chunk W glls ride under the remaining 17 groups of MFMA
        stage_w((c + 1 < NCHUNK) ? c + 1 : NCHUNK - 1, buf ^ 1);
        __builtin_amdgcn_s_setprio(1);
        GRP(0, 1)
        GRP(1, 0) GRP(1, 1)
        GRP(2, 0) GRP(2, 1)
        GRP(3, 0) GRP(3, 1)
        GRP(4, 0) GRP(4, 1)
        GRP(5, 0) GRP(5, 1)
        GRP(6, 0) GRP(6, 1)
        GRP(7, 0) GRP(7, 1)
        GRP(8, 0) GRP(8, 1)
        __builtin_amdgcn_s_setprio(0);

        // drain own glls + B loads; publish W(c+1)
        asm volatile("s_waitcnt vmcnt(0)" ::: "memory");
        __builtin_amdgcn_sched_barrier(0);
        __builtin_amdgcn_s_barrier();
        __builtin_amdgcn_sched_barrier(0);
    }
#undef GRP

    // epilogue: demodulate + store.
    // C/D 32x32 mapping: col(px) = lane&31, row(co) = (r&3)+8*(r>>2)+4*lh.
#pragma unroll
    for (int mf = 0; mf < 4; ++mf) {
#pragma unroll
        for (int nf = 0; nf < 4; ++nf) {
            const int row_out = wave_r + (nf >> 1);
            const int px = (nf & 1) * 32 + l31;
#pragma unroll
            for (int r = 0; r < 16; ++r) {
                int co = ct * 128 + mf * 32 + (r & 3) + 8 * (r >> 2) + 4 * lh;
                float oscv = osc[b * CDIM + co];
                out[((b * CDIM + co) * HW + row_out) * HW + px] = acc[mf][nf][r] * oscv;
            }
        }
    }
}

// ---------------- fallback conv (round-4 proven, reg-staged x, OLD wgt) ------
__global__ __launch_bounds__(512, 1) void conv_main_fb(
    const float* __restrict__ x, const float* __restrict__ s,
    const short* __restrict__ wgt, const float* __restrict__ osc,
    float* __restrict__ out) {

    __shared__ __align__(16) short w_lds[9 * 8 * 64 * 8];
    __shared__ __align__(16) short x_lds[2][10 * 66 * 32];

    const int tid = threadIdx.x;
    const int lane = tid & 63;
    const int wid = tid >> 6;
    const int l15 = lane & 15;
    const int l4 = lane >> 4;

    const int bx = blockIdx.x;
    const int xcd = bx & 7;
    const int t7 = bx >> 3;
    const int ct = t7 & 3;
    const int ghi = t7 >> 2;
    const int b = xcd;
    const int r0 = ghi * 8;

    const int cig = tid & 3;
    const int col = (tid >> 2) & 63;
    const int rowhalf = tid >> 8;

    for (int i = tid; i < 640; i += 512) {
        int bufi = i >= 320;
        int v = i - bufi * 320;
        int row = v >> 5;
        int w16 = v & 31;
        int colh = (w16 >= 16) ? 65 : 0;
        int q16 = w16 & 15;
        ((unsigned*)x_lds[bufi])[(row * 66 + colh) * 16 + q16] = 0u;
    }

    float rx[40];
    float4v sva, svb;

    auto stage_w = [&](int c) {
        const short* src = wgt + (c * 4 + ct) * 36864;
#pragma unroll
        for (int k = 0; k < 9; ++k) {
            int off = (k * 512 + wid * 64) * 8;
            async_ld16(src + off + lane * 8, w_lds + off);
        }
    };

    auto stage_x_load = [&](int c) {
        const float4v* sp = (const float4v*)&s[b * CDIM + c * 32 + cig * 8];
        sva = sp[0]; svb = sp[1];
#pragma unroll
        for (int i = 0; i < 5; ++i) {
            int row = 2 * i + rowhalf;
            int grow = r0 - 1 + row;
            bool ok = (grow >= 0) && (grow < HW);
            const float* base = x + ((b * CDIM + c * 32 + cig * 8) * HW + (ok ? grow : 0)) * HW + col;
#pragma unroll
            for (int j = 0; j < 8; ++j) {
                float v = base[j * (HW * HW)];
                rx[i * 8 + j] = ok ? v : 0.0f;
            }
        }
    };

    auto stage_x_write = [&](int buf) {
        int lcol = col + 1;
        int q = cig ^ ((lcol >> 1) & 3);
#pragma unroll
        for (int i = 0; i < 5; ++i) {
            int row = 2 * i + rowhalf;
            short8 pk;
#pragma unroll
            for (int j = 0; j < 8; ++j) {
                float sj = (j < 4) ? sva[j] : svb[j - 4];
                pk[j] = f2bf(rx[i * 8 + j] * sj);
            }
            *(short8*)&x_lds[buf][(row * 66 + lcol) * 32 + q * 8] = pk;
        }
    };

    float4v acc[8][4] = {};

    auto compute = [&](int buf) {
        const short* xb = x_lds[buf];
#pragma unroll
        for (int t = 0; t < 9; ++t) {
            int dh = t / 3 - 1;
            int dw = t % 3 - 1;
            int lrow = wid + dh + 1;
            short8 bfr[4];
#pragma unroll
            for (int nf = 0; nf < 4; ++nf) {
                int lcol = 1 + nf * 16 + l15 + dw;
                int xq = l4 ^ ((lcol >> 1) & 3);
                bfr[nf] = *(const short8*)&xb[(lrow * 66 + lcol) * 32 + xq * 8];
            }
#pragma unroll
            for (int mf = 0; mf < 8; ++mf) {
                short8 af = *(const short8*)&w_lds[((t * 8 + mf) * 64 + lane) * 8];
#pragma unroll
                for (int nf = 0; nf < 4; ++nf)
                    acc[mf][nf] = __builtin_amdgcn_mfma_f32_16x16x32_bf16(
                        af, bfr[nf], acc[mf][nf], 0, 0, 0);
            }
        }
    };

    stage_w(0);
    stage_x_load(0);
    stage_x_write(0);
    hard_sync();

    int cur = 0;
#pragma unroll 1
    for (int c = 0; c < NCHUNK; ++c) {
        if (c + 1 < NCHUNK) stage_x_load(c + 1);
        compute(cur);
        if (c + 1 < NCHUNK) {
            hard_sync();
            stage_w(c + 1);
            stage_x_write(cur ^ 1);
            hard_sync();
            cur ^= 1;
        }
    }

    const int row_out = r0 + wid;
#pragma unroll
    for (int mf = 0; mf < 8; ++mf) {
        float4v ov = *(const float4v*)&osc[b * CDIM + ct * 128 + mf * 16 + l4 * 4];
#pragma unroll
        for (int j = 0; j < 4; ++j) {
            int co = ct * 128 + mf * 16 + l4 * 4 + j;
            float* po = out + ((b * CDIM + co) * HW + row_out) * HW;
#pragma unroll
            for (int nf = 0; nf < 4; ++nf)
                po[nf * 16 + l15] = acc[mf][nf][j] * ov[j];
        }
    }
}

// ---------------- launcher ----------------

extern "C" void kernel_launch(void* const* d_in, const int* in_sizes, int n_in,
                              void* d_out, int out_size, void* d_ws, size_t ws_size,
                              hipStream_t stream) {
    const float* x     = (const float*)d_in[0];   // 8*512*64*64
    const float* style = (const float*)d_in[1];   // 8*512
    const float* w     = (const float*)d_in[2];   // 512*512*9
    const float* aw    = (const float*)d_in[3];   // 512*512
    const float* ab    = (const float*)d_in[4];   // 512
    float* out = (float*)d_out;

    char* wsb = (char*)d_ws;
    float* s_buf = (float*)(wsb);                 // 16384 B
    float* ws2   = (float*)(wsb + 16384);         // 1048576 B
    float* osc   = (float*)(wsb + 1064960);       // 16384 B
    short* wgt   = (short*)(wsb + 1081344);       // 4718592 B
    short* zrow  = (short*)(wsb + 5799936);       // 4224 B zero row (pad to 4352)
    short* xs    = (short*)(wsb + 5804288);       // 34603008 B
    const size_t need = 5804288ull + 34603008ull; // ~40.4 MB

    k_affine<<<1024, 256, 0, stream>>>(style, aw, ab, s_buf);
    k_ws2<<<1024, 256, 0, stream>>>(w, ws2);
    k_oscale<<<1024, 256, 0, stream>>>(s_buf, ws2, osc);

    if (ws_size >= need) {
        k_wconv32<<<9216, 256, 0, stream>>>(w, wgt);
        hipMemsetAsync(zrow, 0, 4352, stream);
        k_xs<<<8192, 256, 0, stream>>>(x, s_buf, xs);
        conv_main5<<<256, 256, 0, stream>>>(xs, zrow, wgt, osc, out);
    } else {
        k_wconv4<<<9216, 256, 0, stream>>>(w, wgt);
        conv_main_fb<<<256, 512, 0, stream>>>(x, s_buf, wgt, osc, out);
    }
}

// Round 13
// 152.768 us; speedup vs baseline: 1.3743x; 1.3743x over previous
//
#include <hip/hip_runtime.h>
#include <hip/hip_bf16.h>

// ModulatedConv2d: out = oscale[b,co] * conv2d(s[b,ci]*x, w_bf16)
// B=8, C=512, K=3, H=W=64.
// Round 13: revert conv to round-9 optimum (proven 134.7 us; additive-law
// floor: 11.2k MFMA + ~9.6k delivery cyc/chunk). Prep trimmed: k_affine+k_ws2
// fused (one dispatch), zrow memset folded into k_xs block 0.

#define CDIM 512
#define HW 64
#define NCHUNK 16   // 512/32
#define XROW 2112   // shorts per xs row: 66 px-cols * 32 ci

typedef __attribute__((ext_vector_type(8))) short short8;
typedef __attribute__((ext_vector_type(4))) float float4v;

__device__ __forceinline__ short f2bf(float f) {
    unsigned u = __float_as_uint(f);
    unsigned r = (u + 0x7FFFu + ((u >> 16) & 1u)) >> 16;
    return (short)r;
}

__device__ __forceinline__ void async_ld16(const short* g, short* l) {
    __builtin_amdgcn_global_load_lds(
        (const __attribute__((address_space(1))) void*)g,
        (__attribute__((address_space(3))) void*)l, 16, 0, 0);
}

__device__ __forceinline__ void hard_sync() {
    asm volatile("s_waitcnt vmcnt(0) lgkmcnt(0)" ::: "memory");
    __builtin_amdgcn_sched_barrier(0);
    __builtin_amdgcn_s_barrier();
    __builtin_amdgcn_sched_barrier(0);
}

// ---------------- prep kernels ----------------

// Fused: (a) ws2[i] = sum_t w[i*9+t]^2 for this block's 256 i's;
//        (b) 4 waves/block each compute one s[b][ci] dot-product.
__global__ void k_prep(const float* __restrict__ w, float* __restrict__ ws2,
                       const float* __restrict__ style, const float* __restrict__ aw,
                       const float* __restrict__ ab, float* __restrict__ s) {
    // part (a): ws2
    int i = blockIdx.x * 256 + threadIdx.x;  // 262144 over 1024 blocks
    const float* p = w + i * 9;
    float a = 0.f;
#pragma unroll
    for (int t = 0; t < 9; ++t) a += p[t] * p[t];
    ws2[i] = a;

    // part (b): affine
    int gid = blockIdx.x * 4 + (threadIdx.x >> 6);   // 0..4095
    int lane = threadIdx.x & 63;
    int b = gid >> 9, ci = gid & 511;
    const float4v* st = (const float4v*)(style + b * CDIM);
    const float4v* wp = (const float4v*)(aw + ci * CDIM);
    float acc = 0.f;
#pragma unroll
    for (int k = 0; k < 2; ++k) {
        float4v av = st[lane * 2 + k], wv = wp[lane * 2 + k];
        acc += av[0] * wv[0] + av[1] * wv[1] + av[2] * wv[2] + av[3] * wv[3];
    }
#pragma unroll
    for (int off = 32; off; off >>= 1) acc += __shfl_down(acc, off);
    if (lane == 0) s[gid] = acc * 0.04419417382415922f + ab[ci];
}

// one wave per (b,co): oscale = wg*rsqrt(wg^2*sum_ci s^2*ws2 + 1e-8)
__global__ void k_oscale(const float* __restrict__ s, const float* __restrict__ ws2,
                         float* __restrict__ osc) {
    int gid = blockIdx.x * 4 + (threadIdx.x >> 6);   // 0..4095
    int lane = threadIdx.x & 63;
    int b = gid >> 9, co = gid & 511;
    const float4v* sp = (const float4v*)(s + b * CDIM);
    const float4v* rp = (const float4v*)(ws2 + co * CDIM);
    float acc = 0.f;
#pragma unroll
    for (int k = 0; k < 2; ++k) {
        float4v a = sp[lane * 2 + k], r = rp[lane * 2 + k];
        acc += a[0] * a[0] * r[0] + a[1] * a[1] * r[1]
             + a[2] * a[2] * r[2] + a[3] * a[3] * r[3];
    }
#pragma unroll
    for (int off = 32; off; off >>= 1) acc += __shfl_down(acc, off);
    const float wg = 0.014731391274719739f;          // 1/sqrt(4608)
    const float wg2 = 2.170138888888889e-4f;         // 1/4608
    if (lane == 0) osc[gid] = wg * rsqrtf(wg2 * acc + 1e-8f);
}

// wgt layout: [chunk16][ct4] regions of 36864 shorts.
// Within region: [t9][mf8][slot64][j8], slot = l4*16 + l15 (lane-linear),
// value = w[co = ct*128 + mf*16 + l15][ci = chunk*32 + l4*8 + j][t]
__global__ void k_wconv(const float* __restrict__ w, short* __restrict__ wgt) {
    int idx = blockIdx.x * 256 + threadIdx.x;  // 2359296
    int j = idx & 7;
    int slotg = idx >> 3;
    int region = slotg / 4608;         // chunk*4 + ct
    int a16 = slotg - region * 4608;
    int tm = a16 >> 6;                 // t*8 + mf
    int t = tm >> 3;
    int mf = tm & 7;
    int sl = a16 & 63;
    int l4 = sl >> 4;
    int l15 = sl & 15;
    int ct = region & 3;
    int c = region >> 2;
    int co = ct * 128 + mf * 16 + l15;
    int ci = c * 32 + l4 * 8 + j;
    wgt[idx] = f2bf(w[(co * CDIM + ci) * 9 + t]);
}

// xs layout: [b8][c16][grow64] rows of XROW=2112 shorts (66 px-cols x 32 ci):
// shorts at (px+1)*32 + sl*8 + j = bf16( x[b][ci=c*32+sl*8+j][grow][px] * s ),
// px-cols 0 and 65 are zero halos. Block 0 also zero-fills zrow.
__global__ void k_xs(const float* __restrict__ x, const float* __restrict__ s,
                     short* __restrict__ xs, short* __restrict__ zrow) {
    const int bx = blockIdx.x;         // (b*16 + c)*64 + grow
    if (bx == 0) {                     // zero page for OOB rows (528 short8)
        short8 z = {};
        for (int u = threadIdx.x; u < 528; u += 256)
            *(short8*)&zrow[u * 8] = z;
    }
    const int grow = bx & 63;
    const int t = bx >> 6;
    const int c = t & 15;
    const int b = t >> 4;
    const int px = threadIdx.x >> 2;   // 0..63
    const int sl = threadIdx.x & 3;    // ci 8-group
    const int ci0 = c * 32 + sl * 8;
    const float* xb = x + ((b * CDIM + ci0) * HW + grow) * HW + px;
    const float* sb = s + b * CDIM + ci0;
    short8 pk;
#pragma unroll
    for (int j = 0; j < 8; ++j)
        pk[j] = f2bf(xb[j * (HW * HW)] * sb[j]);
    short* rowp = xs + (size_t)bx * XROW;
    *(short8*)&rowp[(px + 1) * 32 + sl * 8] = pk;
    if (threadIdx.x < 8) {             // zero halo cols 0 and 65
        int col = (threadIdx.x >> 2) ? 65 : 0;
        int s2 = threadIdx.x & 3;
        short8 z = {};
        *(short8*)&rowp[col * 32 + s2 * 8] = z;
    }
}

// ---------------- main conv (round-9 optimum: B from L2, W dbuf in LDS) -----
// grid 256 blocks x 512 threads. Block: (ct co-tile of 128, b, row-tile of 8).
// Wave = one output row: 128co x 64px.
__global__ __launch_bounds__(512, 1) void conv_main3(
    const short* __restrict__ xs, const short* __restrict__ zrow,
    const short* __restrict__ wgt, const float* __restrict__ osc,
    float* __restrict__ out) {

    __shared__ __align__(16) short w_lds[2][36864];   // 2 x 73728 B

    const int tid = threadIdx.x;
    const int lane = tid & 63;
    const int wr = tid >> 6;           // 0..7 = output row within tile
    const int l15 = lane & 15;
    const int l4 = lane >> 4;

    // b == xcd; the 4 ct-blocks of one (b,rt) group share the xs slice in L2.
    const int bx = blockIdx.x;
    const int xcd = bx & 7;
    const int t7 = bx >> 3;
    const int ct = t7 & 3;
    const int ghi = t7 >> 2;           // 0..7
    const int b = xcd;
    const int r0 = ghi * 8;

    const int voff = l15 * 32 + l4 * 8;   // lane-affine B offset (shorts)

    auto stage_w = [&](int c, int bufn) {   // 9 glls/wave
        const short* src = wgt + (c * 4 + ct) * 36864;
        short* dstb = &w_lds[bufn][0];
#pragma unroll
        for (int k = 0; k < 9; ++k) {
            int off = (k * 512 + wr * 64) * 8;
            async_ld16(src + off + lane * 8, dstb + off + lane * 8);
        }
    };

    float4v acc[8][4] = {};

#define TAPX(T)                                                                  \
    { const short* pd = ((T) < 3) ? p0 : (((T) < 6) ? p1 : p2);                  \
      const int dwp1 = (T) % 3;    /* dw+1: 0,1,2 */                             \
      short8 bfr[4];                                                             \
      _Pragma("unroll")                                                          \
      for (int nf = 0; nf < 4; ++nf)                                             \
          bfr[nf] = *(const short8*)(pd + voff + (nf * 16 + dwp1) * 32);         \
      _Pragma("unroll")                                                          \
      for (int mf = 0; mf < 8; ++mf) {                                           \
          short8 af = *(const short8*)&wb[(((T) * 8 + mf) * 64 + lane) * 8];     \
          _Pragma("unroll")                                                      \
          for (int nf = 0; nf < 4; ++nf)                                         \
              acc[mf][nf] = __builtin_amdgcn_mfma_f32_16x16x32_bf16(             \
                  af, bfr[nf], acc[mf][nf], 0, 0, 0);                            \
      } }

    // prologue: W(0) -> buf0, drain, publish
    stage_w(0, 0);
    hard_sync();

    const int gb = r0 + wr - 1;        // grow of dh=0 row for this wave
#pragma unroll 1
    for (int c = 0; c < NCHUNK; ++c) {
        const int buf = c & 1;
        const short* wb = &w_lds[buf][0];
        const short* xcb = xs + ((size_t)(b * 16 + c) * 64) * XROW;
        const short* p0 = ((unsigned)(gb + 0) < 64u) ? xcb + (size_t)(gb + 0) * XROW : zrow;
        const short* p1 = ((unsigned)(gb + 1) < 64u) ? xcb + (size_t)(gb + 1) * XROW : zrow;
        const short* p2 = ((unsigned)(gb + 2) < 64u) ? xcb + (size_t)(gb + 2) * XROW : zrow;

        TAPX(0)
        // next-chunk W glls ride under taps 1..8 (~10k cyc of MFMA)
        stage_w((c + 1 < NCHUNK) ? c + 1 : NCHUNK - 1, buf ^ 1);
        __builtin_amdgcn_s_setprio(1);
        TAPX(1) TAPX(2) TAPX(3) TAPX(4)
        TAPX(5) TAPX(6) TAPX(7) TAPX(8)
        __builtin_amdgcn_s_setprio(0);

        // drain own glls (landed under MFMA) ; publish W(c+1)
        asm volatile("s_waitcnt vmcnt(0)" ::: "memory");
        __builtin_amdgcn_sched_barrier(0);
        __builtin_amdgcn_s_barrier();
        __builtin_amdgcn_sched_barrier(0);
    }
#undef TAPX

    // epilogue: demodulate + store
    const int row_out = r0 + wr;
#pragma unroll
    for (int mf = 0; mf < 8; ++mf) {
        float4v ov = *(const float4v*)&osc[b * CDIM + ct * 128 + mf * 16 + l4 * 4];
#pragma unroll
        for (int j = 0; j < 4; ++j) {
            int co = ct * 128 + mf * 16 + l4 * 4 + j;
            float* po = out + ((b * CDIM + co) * HW + row_out) * HW;
#pragma unroll
            for (int nf = 0; nf < 4; ++nf)
                po[nf * 16 + l15] = acc[mf][nf][j] * ov[j];
        }
    }
}

// ---------------- fallback conv (round-4 proven, reg-staged x) ----------------
__global__ __launch_bounds__(512, 1) void conv_main_fb(
    const float* __restrict__ x, const float* __restrict__ s,
    const short* __restrict__ wgt, const float* __restrict__ osc,
    float* __restrict__ out) {

    __shared__ __align__(16) short w_lds[9 * 8 * 64 * 8];
    __shared__ __align__(16) short x_lds[2][10 * 66 * 32];

    const int tid = threadIdx.x;
    const int lane = tid & 63;
    const int wid = tid >> 6;
    const int l15 = lane & 15;
    const int l4 = lane >> 4;

    const int bx = blockIdx.x;
    const int xcd = bx & 7;
    const int t7 = bx >> 3;
    const int ct = t7 & 3;
    const int ghi = t7 >> 2;
    const int b = xcd;
    const int r0 = ghi * 8;

    const int cig = tid & 3;
    const int col = (tid >> 2) & 63;
    const int rowhalf = tid >> 8;

    for (int i = tid; i < 640; i += 512) {
        int bufi = i >= 320;
        int v = i - bufi * 320;
        int row = v >> 5;
        int w16 = v & 31;
        int colh = (w16 >= 16) ? 65 : 0;
        int q16 = w16 & 15;
        ((unsigned*)x_lds[bufi])[(row * 66 + colh) * 16 + q16] = 0u;
    }

    float rx[40];
    float4v sva, svb;

    auto stage_w = [&](int c) {
        const short* src = wgt + (c * 4 + ct) * 36864;
#pragma unroll
        for (int k = 0; k < 9; ++k) {
            int off = (k * 512 + wid * 64) * 8;
            async_ld16(src + off + lane * 8, w_lds + off);
        }
    };

    auto stage_x_load = [&](int c) {
        const float4v* sp = (const float4v*)&s[b * CDIM + c * 32 + cig * 8];
        sva = sp[0]; svb = sp[1];
#pragma unroll
        for (int i = 0; i < 5; ++i) {
            int row = 2 * i + rowhalf;
            int grow = r0 - 1 + row;
            bool ok = (grow >= 0) && (grow < HW);
            const float* base = x + ((b * CDIM + c * 32 + cig * 8) * HW + (ok ? grow : 0)) * HW + col;
#pragma unroll
            for (int j = 0; j < 8; ++j) {
                float v = base[j * (HW * HW)];
                rx[i * 8 + j] = ok ? v : 0.0f;
            }
        }
    };

    auto stage_x_write = [&](int buf) {
        int lcol = col + 1;
        int q = cig ^ ((lcol >> 1) & 3);
#pragma unroll
        for (int i = 0; i < 5; ++i) {
            int row = 2 * i + rowhalf;
            short8 pk;
#pragma unroll
            for (int j = 0; j < 8; ++j) {
                float sj = (j < 4) ? sva[j] : svb[j - 4];
                pk[j] = f2bf(rx[i * 8 + j] * sj);
            }
            *(short8*)&x_lds[buf][(row * 66 + lcol) * 32 + q * 8] = pk;
        }
    };

    float4v acc[8][4] = {};

    auto compute = [&](int buf) {
        const short* xb = x_lds[buf];
#pragma unroll
        for (int t = 0; t < 9; ++t) {
            int dh = t / 3 - 1;
            int dw = t % 3 - 1;
            int lrow = wid + dh + 1;
            short8 bfr[4];
#pragma unroll
            for (int nf = 0; nf < 4; ++nf) {
                int lcol = 1 + nf * 16 + l15 + dw;
                int xq = l4 ^ ((lcol >> 1) & 3);
                bfr[nf] = *(const short8*)&xb[(lrow * 66 + lcol) * 32 + xq * 8];
            }
#pragma unroll
            for (int mf = 0; mf < 8; ++mf) {
                short8 af = *(const short8*)&w_lds[((t * 8 + mf) * 64 + lane) * 8];
#pragma unroll
                for (int nf = 0; nf < 4; ++nf)
                    acc[mf][nf] = __builtin_amdgcn_mfma_f32_16x16x32_bf16(
                        af, bfr[nf], acc[mf][nf], 0, 0, 0);
            }
        }
    };

    stage_w(0);
    stage_x_load(0);
    stage_x_write(0);
    hard_sync();

    int cur = 0;
#pragma unroll 1
    for (int c = 0; c < NCHUNK; ++c) {
        if (c + 1 < NCHUNK) stage_x_load(c + 1);
        compute(cur);
        if (c + 1 < NCHUNK) {
            hard_sync();
            stage_w(c + 1);
            stage_x_write(cur ^ 1);
            hard_sync();
            cur ^= 1;
        }
    }

    const int row_out = r0 + wid;
#pragma unroll
    for (int mf = 0; mf < 8; ++mf) {
        float4v ov = *(const float4v*)&osc[b * CDIM + ct * 128 + mf * 16 + l4 * 4];
#pragma unroll
        for (int j = 0; j < 4; ++j) {
            int co = ct * 128 + mf * 16 + l4 * 4 + j;
            float* po = out + ((b * CDIM + co) * HW + row_out) * HW;
#pragma unroll
            for (int nf = 0; nf < 4; ++nf)
                po[nf * 16 + l15] = acc[mf][nf][j] * ov[j];
        }
    }
}

// ---------------- launcher ----------------

extern "C" void kernel_launch(void* const* d_in, const int* in_sizes, int n_in,
                              void* d_out, int out_size, void* d_ws, size_t ws_size,
                              hipStream_t stream) {
    const float* x     = (const float*)d_in[0];   // 8*512*64*64
    const float* style = (const float*)d_in[1];   // 8*512
    const float* w     = (const float*)d_in[2];   // 512*512*9
    const float* aw    = (const float*)d_in[3];   // 512*512
    const float* ab    = (const float*)d_in[4];   // 512
    float* out = (float*)d_out;

    char* wsb = (char*)d_ws;
    float* s_buf = (float*)(wsb);                 // 16384 B
    float* ws2   = (float*)(wsb + 16384);         // 1048576 B
    float* osc   = (float*)(wsb + 1064960);       // 16384 B
    short* wgt   = (short*)(wsb + 1081344);       // 4718592 B
    short* zrow  = (short*)(wsb + 5799936);       // 4224 B zero row (pad to 4352)
    short* xs    = (short*)(wsb + 5804288);       // 34603008 B
    const size_t need = 5804288ull + 34603008ull; // ~40.4 MB

    k_prep<<<1024, 256, 0, stream>>>(w, ws2, style, aw, ab, s_buf);
    k_wconv<<<9216, 256, 0, stream>>>(w, wgt);
    k_oscale<<<1024, 256, 0, stream>>>(s_buf, ws2, osc);

    if (ws_size >= need) {
        k_xs<<<8192, 256, 0, stream>>>(x, s_buf, xs, zrow);
        conv_main3<<<256, 512, 0, stream>>>(xs, zrow, wgt, osc, out);
    } else {
        conv_main_fb<<<256, 512, 0, stream>>>(x, s_buf, wgt, osc, out);
    }
}